// Round 1
// baseline (5904.526 us; speedup 1.0000x reference)
//
#include <hip/hip_runtime.h>
#include <hip/hip_bf16.h>

typedef __bf16 bf16x8 __attribute__((ext_vector_type(8)));
typedef __bf16 bf16x2 __attribute__((ext_vector_type(2)));
typedef float  f32x4  __attribute__((ext_vector_type(4)));

// ---------------------------------------------------------------- pack W
// Layout: [li=L*9+i][ks(8)][cf(8)][lane(64)][j(8)]  (bf16)
// k = ks*32 + (lane>>4)*8 + j ; col = cf*16 + (lane&15)
// k < 128 -> W_rel[li][k][col], else W_root[li][k-128][col]
__global__ void __launch_bounds__(256) pack_w(const float* __restrict__ Wrel,
                                              const float* __restrict__ Wroot,
                                              __bf16* __restrict__ Wp)
{
    const int idx = blockIdx.x * 256 + threadIdx.x;
    if (idx >= 2 * 9 * 8 * 8 * 64) return;
    const int lane = idx & 63;
    int t = idx >> 6;
    const int cf = t & 7; t >>= 3;
    const int ks = t & 7; t >>= 3;
    const int li = t;  // 0..17
    const int col = cf * 16 + (lane & 15);
    const int kb  = ks * 32 + (lane >> 4) * 8;
    bf16x8 o;
#pragma unroll
    for (int j = 0; j < 8; ++j) {
        const int k = kb + j;
        const float v = (k < 128)
            ? Wrel [((size_t)li * 128 + k)        * 128 + col]
            : Wroot[((size_t)li * 128 + (k - 128)) * 128 + col];
        o[j] = (__bf16)v;
    }
    *reinterpret_cast<bf16x8*>(Wp + (size_t)idx * 8) = o;
}

// ---------------------------------------------------------------- scatter
// agg[dst] += x_src[src]; one wave per edge, 2 floats/lane.
template<bool SRC_BF16>
__global__ void __launch_bounds__(256) scatter_kernel(const void* __restrict__ xsrc,
                                                      const int* __restrict__ ei, int E,
                                                      float* __restrict__ agg)
{
    const int lane = threadIdx.x & 63;
    const int gw = (blockIdx.x * 256 + threadIdx.x) >> 6;
    const int nw = (gridDim.x * 256) >> 6;
    for (int e = gw; e < E; e += nw) {
        const int s = ei[e];
        const int d = ei[E + e];
        float vx, vy;
        if constexpr (SRC_BF16) {
            const bf16x2 v = *reinterpret_cast<const bf16x2*>(
                (const __bf16*)xsrc + (size_t)s * 128 + lane * 2);
            vx = (float)v[0]; vy = (float)v[1];
        } else {
            const float2 v = *reinterpret_cast<const float2*>(
                (const float*)xsrc + (size_t)s * 128 + lane * 2);
            vx = v.x; vy = v.y;
        }
        float* ap = agg + (size_t)d * 128 + lane * 2;
        atomicAdd(ap, vx);
        atomicAdd(ap + 1, vy);
    }
}

// ---------------------------------------------------------------- GEMM + BN stats
// h[M,128] = [agg | x_dst](M,256) @ Wp(256,128) + bias ; stats[0:128]=colsum(h), [128:256]=colsum(h^2)
// block = 256 thr (4 waves), tile = 128 rows; wave w owns rows w*32..w*32+31 (2 row-frags),
// all 8 col-frags. 16x16x32 bf16 MFMA. A direct from global, B from packed global (L2).
template<bool XBF16>
__global__ void __launch_bounds__(256) gemm_kernel(const float* __restrict__ agg,
                                                   const void* __restrict__ xdst,
                                                   const __bf16* __restrict__ Wp,
                                                   const float* __restrict__ bias,
                                                   __bf16* __restrict__ hout,
                                                   float* __restrict__ stats, int M)
{
    __shared__ float lsum[128];
    __shared__ float lsq[128];
    const int tid  = threadIdx.x;
    const int lane = tid & 63;
    const int wv   = tid >> 6;
    if (tid < 128) { lsum[tid] = 0.f; lsq[tid] = 0.f; }
    __syncthreads();

    const int r0    = blockIdx.x * 128 + wv * 32;
    const int lrow  = lane & 15;
    const int klane = (lane >> 4) * 8;

    int  car[2]; bool val[2];
#pragma unroll
    for (int rf = 0; rf < 2; ++rf) {
        const int ar = r0 + rf * 16 + lrow;
        val[rf] = ar < M;
        car[rf] = val[rf] ? ar : (M - 1);
    }

    bf16x8 z8;
#pragma unroll
    for (int j = 0; j < 8; ++j) z8[j] = (__bf16)0.f;

    f32x4 acc[2][8];
#pragma unroll
    for (int rf = 0; rf < 2; ++rf)
#pragma unroll
        for (int cf = 0; cf < 8; ++cf) {
            f32x4 z; z[0] = 0.f; z[1] = 0.f; z[2] = 0.f; z[3] = 0.f;
            acc[rf][cf] = z;
        }

    const __bf16* xb = (const __bf16*)xdst;
    const float*  xf = (const float*)xdst;

#pragma unroll
    for (int ks = 0; ks < 8; ++ks) {
        const int koff = (ks & 3) * 32 + klane;
        bf16x8 a[2];
#pragma unroll
        for (int rf = 0; rf < 2; ++rf) {
            if (ks < 4 || !XBF16) {
                const float* ap = (ks < 4 ? agg : xf) + (size_t)car[rf] * 128 + koff;
                const float4 f0 = *reinterpret_cast<const float4*>(ap);
                const float4 f1 = *reinterpret_cast<const float4*>(ap + 4);
                bf16x8 av;
                av[0] = (__bf16)f0.x; av[1] = (__bf16)f0.y; av[2] = (__bf16)f0.z; av[3] = (__bf16)f0.w;
                av[4] = (__bf16)f1.x; av[5] = (__bf16)f1.y; av[6] = (__bf16)f1.z; av[7] = (__bf16)f1.w;
                a[rf] = val[rf] ? av : z8;
            } else {
                const bf16x8 av = *reinterpret_cast<const bf16x8*>(
                    xb + (size_t)car[rf] * 128 + koff);
                a[rf] = val[rf] ? av : z8;
            }
        }
        const bf16x8* wp8 = reinterpret_cast<const bf16x8*>(Wp) + (size_t)ks * 8 * 64 + lane;
        bf16x8 b[8];
#pragma unroll
        for (int cf = 0; cf < 8; ++cf) b[cf] = wp8[(size_t)cf * 64];
#pragma unroll
        for (int rf = 0; rf < 2; ++rf)
#pragma unroll
            for (int cf = 0; cf < 8; ++cf)
                acc[rf][cf] = __builtin_amdgcn_mfma_f32_16x16x32_bf16(a[rf], b[cf], acc[rf][cf], 0, 0, 0);
    }

    float bc[8];
#pragma unroll
    for (int cf = 0; cf < 8; ++cf) bc[cf] = bias[cf * 16 + lrow];

    const int rb = (lane >> 4) * 4;
#pragma unroll
    for (int cf = 0; cf < 8; ++cf) {
        float s = 0.f, q = 0.f;
#pragma unroll
        for (int rf = 0; rf < 2; ++rf) {
#pragma unroll
            for (int rr = 0; rr < 4; ++rr) {
                const int grow = r0 + rf * 16 + rb + rr;
                if (grow < M) {
                    const float hv = acc[rf][cf][rr] + bc[cf];
                    hout[(size_t)grow * 128 + cf * 16 + lrow] = (__bf16)hv;
                    s += hv; q += hv * hv;
                }
            }
        }
        s += __shfl_xor(s, 16); s += __shfl_xor(s, 32);
        q += __shfl_xor(q, 16); q += __shfl_xor(q, 32);
        if (lane < 16) {
            atomicAdd(&lsum[cf * 16 + lane], s);
            atomicAdd(&lsq [cf * 16 + lane], q);
        }
    }
    __syncthreads();
    if (tid < 128) {
        atomicAdd(&stats[tid],       lsum[tid]);
        atomicAdd(&stats[128 + tid], lsq[tid]);
    }
}

// ---------------------------------------------------------------- BN prep
__global__ void prep_kernel(const float* __restrict__ stats,
                            const float* __restrict__ gamma,
                            const float* __restrict__ beta,
                            float* __restrict__ ss, float invM)
{
    const int c = threadIdx.x;
    const float mu   = stats[c] * invM;
    const float var  = stats[128 + c] * invM - mu * mu;
    const float scal = gamma[c] * rsqrtf(var + 1e-5f);
    ss[c]       = scal;
    ss[128 + c] = beta[c] - mu * scal;
}

// ---------------------------------------------------------------- normalize + accumulate
// MODE 0: out(bf16) = v ; MODE 1: out(bf16) += v ; MODE 2: out(f32) += v
template<int MODE>
__global__ void __launch_bounds__(256) norm_kernel(const __bf16* __restrict__ h,
                                                   const float* __restrict__ ss,
                                                   void* __restrict__ out, int M)
{
    const int t0   = blockIdx.x * 256 + threadIdx.x;
    const int nthr = gridDim.x * 256;
    const int c0   = (t0 & 15) * 8;
    float sc[8], sh[8];
#pragma unroll
    for (int j = 0; j < 8; ++j) { sc[j] = ss[c0 + j]; sh[j] = ss[128 + c0 + j]; }
    const int nch = M * 16;
    for (int ch = t0; ch < nch; ch += nthr) {
        const bf16x8 hv = *reinterpret_cast<const bf16x8*>(h + (size_t)ch * 8);
        float f[8];
#pragma unroll
        for (int j = 0; j < 8; ++j) f[j] = (float)hv[j] * sc[j] + sh[j];
        if constexpr (MODE == 0) {
            bf16x8 ov;
#pragma unroll
            for (int j = 0; j < 8; ++j) ov[j] = (__bf16)f[j];
            *reinterpret_cast<bf16x8*>((__bf16*)out + (size_t)ch * 8) = ov;
        } else if constexpr (MODE == 1) {
            __bf16* op = (__bf16*)out + (size_t)ch * 8;
            bf16x8 ov = *reinterpret_cast<const bf16x8*>(op);
#pragma unroll
            for (int j = 0; j < 8; ++j) ov[j] = (__bf16)((float)ov[j] + f[j]);
            *reinterpret_cast<bf16x8*>(op) = ov;
        } else {
            float* op = (float*)out + (size_t)ch * 8;
            float4 o0 = *reinterpret_cast<float4*>(op);
            float4 o1 = *reinterpret_cast<float4*>(op + 4);
            o0.x += f[0]; o0.y += f[1]; o0.z += f[2]; o0.w += f[3];
            o1.x += f[4]; o1.y += f[5]; o1.z += f[6]; o1.w += f[7];
            *reinterpret_cast<float4*>(op)     = o0;
            *reinterpret_cast<float4*>(op + 4) = o1;
        }
    }
}

// ---------------------------------------------------------------- launch
extern "C" void kernel_launch(void* const* d_in, const int* in_sizes, int n_in,
                              void* d_out, int out_size, void* d_ws, size_t ws_size,
                              hipStream_t stream)
{
    const float* xin[3] = {(const float*)d_in[0], (const float*)d_in[1], (const float*)d_in[2]};
    const int N[3] = {in_sizes[0] / 128, in_sizes[1] / 128, in_sizes[2] / 128};
    const float* Wrel  = (const float*)d_in[12];
    const float* brel  = (const float*)d_in[13];
    const float* Wroot = (const float*)d_in[14];
    const float* gamma = (const float*)d_in[15];
    const float* beta  = (const float*)d_in[16];

    // ETS order: a2b b2a a2g g2a b2g g2b a2a b2b g2g  (atom=0,bond=1,global=2)
    const int cs[9] = {0, 1, 0, 2, 1, 2, 0, 1, 2};
    const int cd[9] = {1, 0, 2, 0, 2, 1, 0, 1, 2};

    const size_t nA = (size_t)N[0] * 128, nB = (size_t)N[1] * 128, nG = (size_t)N[2] * 128;
    const size_t off[3] = {0, nA, nA + nB};
    const size_t xtot = nA + nB + nG;
    size_t maxN = (size_t)N[0];
    if ((size_t)N[1] > maxN) maxN = N[1];
    if ((size_t)N[2] > maxN) maxN = N[2];

    // ws layout (~258 MB): x1(bf16) | agg(f32,maxN) | h(bf16,maxN) | stats | ss | Wp(bf16)
    char* w = (char*)d_ws;
    __bf16* x1    = (__bf16*)w;  w += xtot * 2;
    float*  agg   = (float*)w;   w += maxN * 128 * 4;
    __bf16* hbuf  = (__bf16*)w;  w += maxN * 128 * 2;
    float*  stats = (float*)w;   w += 256 * 4;
    float*  ss    = (float*)w;   w += 256 * 4;
    __bf16* Wp    = (__bf16*)w;
    (void)ws_size; (void)n_in; (void)out_size;

    pack_w<<<288, 256, 0, stream>>>(Wrel, Wroot, Wp);

    float* dout = (float*)d_out;

    for (int L = 0; L < 2; ++L) {
        if (L == 1) {  // seed layer-2 accumulators with the residual (original inputs)
            hipMemcpyAsync(dout + off[0], xin[0], nA * 4, hipMemcpyDeviceToDevice, stream);
            hipMemcpyAsync(dout + off[1], xin[1], nB * 4, hipMemcpyDeviceToDevice, stream);
            hipMemcpyAsync(dout + off[2], xin[2], nG * 4, hipMemcpyDeviceToDevice, stream);
        }
        for (int i = 0; i < 9; ++i) {
            const int s = cs[i], d = cd[i];
            const int E = in_sizes[3 + i] / 2;
            const int* ei = (const int*)d_in[3 + i];

            hipMemsetAsync(agg, 0, (size_t)N[d] * 128 * 4, stream);
            int sb = (E + 3) / 4; if (sb > 2048) sb = 2048; if (sb < 1) sb = 1;
            if (L == 0) scatter_kernel<false><<<sb, 256, 0, stream>>>(xin[s], ei, E, agg);
            else        scatter_kernel<true ><<<sb, 256, 0, stream>>>(x1 + off[s], ei, E, agg);

            hipMemsetAsync(stats, 0, 256 * 4, stream);
            const int gb = (N[d] + 127) / 128;
            const int li = L * 9 + i;
            if (L == 0)
                gemm_kernel<false><<<gb, 256, 0, stream>>>(agg, (const void*)xin[d],
                    Wp + (size_t)li * 32768, brel + li * 128, hbuf, stats, N[d]);
            else
                gemm_kernel<true ><<<gb, 256, 0, stream>>>(agg, (const void*)(x1 + off[d]),
                    Wp + (size_t)li * 32768, brel + li * 128, hbuf, stats, N[d]);

            prep_kernel<<<1, 128, 0, stream>>>(stats, gamma + li * 128, beta + li * 128,
                                               ss, 1.0f / (float)N[d]);

            const long long nch = (long long)N[d] * 16;
            int nb = (int)((nch + 255) / 256); if (nb > 2048) nb = 2048;
            if (L == 0) {
                if (i < 3) norm_kernel<0><<<nb, 256, 0, stream>>>(hbuf, ss, (void*)(x1 + off[d]), N[d]);
                else       norm_kernel<1><<<nb, 256, 0, stream>>>(hbuf, ss, (void*)(x1 + off[d]), N[d]);
            } else {
                norm_kernel<2><<<nb, 256, 0, stream>>>(hbuf, ss, (void*)(dout + off[d]), N[d]);
            }
        }
    }
}

// Round 2
// 2738.678 us; speedup vs baseline: 2.1560x; 2.1560x over previous
//
#include <hip/hip_runtime.h>
#include <hip/hip_bf16.h>

typedef __bf16 bf16x8 __attribute__((ext_vector_type(8)));
typedef float  f32x4  __attribute__((ext_vector_type(4)));

// ---------------------------------------------------------------- pack W
// Layout: [li=L*9+i][ks(8)][cf(8)][lane(64)][j(8)]  (bf16)
// k = ks*32 + (lane>>4)*8 + j ; col = cf*16 + (lane&15)
// k < 128 -> W_rel[li][k][col], else W_root[li][k-128][col]
__global__ void __launch_bounds__(256) pack_w(const float* __restrict__ Wrel,
                                              const float* __restrict__ Wroot,
                                              __bf16* __restrict__ Wp)
{
    const int idx = blockIdx.x * 256 + threadIdx.x;
    if (idx >= 2 * 9 * 8 * 8 * 64) return;
    const int lane = idx & 63;
    int t = idx >> 6;
    const int cf = t & 7; t >>= 3;
    const int ks = t & 7; t >>= 3;
    const int li = t;  // 0..17
    const int col = cf * 16 + (lane & 15);
    const int kb  = ks * 32 + (lane >> 4) * 8;
    bf16x8 o;
#pragma unroll
    for (int j = 0; j < 8; ++j) {
        const int k = kb + j;
        const float v = (k < 128)
            ? Wrel [((size_t)li * 128 + k)        * 128 + col]
            : Wroot[((size_t)li * 128 + (k - 128)) * 128 + col];
        o[j] = (__bf16)v;
    }
    *reinterpret_cast<bf16x8*>(Wp + (size_t)idx * 8) = o;
}

// ---------------------------------------------------------------- scatter
// agg(bf16)[dst] += x_src[src]; one wave per edge, one packed-bf16x2 atomic per lane.
__device__ __forceinline__ void pk_atomic(__bf16* p, uint32_t pk)
{
    const uint64_t addr = (uint64_t)p;
    asm volatile("global_atomic_pk_add_bf16 %0, %1, off" :: "v"(addr), "v"(pk) : "memory");
}

__global__ void __launch_bounds__(256) scatter_f32(const float* __restrict__ xsrc,
                                                   const int* __restrict__ ei, int E,
                                                   __bf16* __restrict__ agg)
{
    const int lane = threadIdx.x & 63;
    const int gw = (blockIdx.x * 256 + threadIdx.x) >> 6;
    const int nw = (gridDim.x * 256) >> 6;
    for (int e = gw; e < E; e += nw) {
        const int s = ei[e];
        const int d = ei[E + e];
        const float2 v = *reinterpret_cast<const float2*>(xsrc + (size_t)s * 128 + lane * 2);
        union { __bf16 b[2]; uint32_t u; } cv;
        cv.b[0] = (__bf16)v.x; cv.b[1] = (__bf16)v.y;
        pk_atomic(agg + (size_t)d * 128 + lane * 2, cv.u);
    }
}

__global__ void __launch_bounds__(256) scatter_bf16(const __bf16* __restrict__ xsrc,
                                                    const int* __restrict__ ei, int E,
                                                    __bf16* __restrict__ agg)
{
    const int lane = threadIdx.x & 63;
    const int gw = (blockIdx.x * 256 + threadIdx.x) >> 6;
    const int nw = (gridDim.x * 256) >> 6;
    for (int e = gw; e < E; e += nw) {
        const int s = ei[e];
        const int d = ei[E + e];
        const uint32_t pk = *reinterpret_cast<const uint32_t*>(xsrc + (size_t)s * 128 + lane * 2);
        pk_atomic(agg + (size_t)d * 128 + lane * 2, pk);
    }
}

// ---------------------------------------------------------------- GEMM + BN stats
// h[M,128] = [agg | x_dst](M,256) @ Wp(256,128) + bias ; stats[0:128]=colsum(h), [128:256]=colsum(h^2)
// block = 256 thr (4 waves), tile = 128 rows; wave w owns rows w*32..w*32+31 (2 row-frags),
// all 8 col-frags. 16x16x32 bf16 MFMA. A direct from global, B from packed global (L2).
template<bool XBF16>
__global__ void __launch_bounds__(256) gemm_kernel(const __bf16* __restrict__ agg,
                                                   const void* __restrict__ xdst,
                                                   const __bf16* __restrict__ Wp,
                                                   const float* __restrict__ bias,
                                                   __bf16* __restrict__ hout,
                                                   float* __restrict__ stats, int M)
{
    __shared__ float lsum[128];
    __shared__ float lsq[128];
    const int tid  = threadIdx.x;
    const int lane = tid & 63;
    const int wv   = tid >> 6;
    if (tid < 128) { lsum[tid] = 0.f; lsq[tid] = 0.f; }
    __syncthreads();

    const int r0    = blockIdx.x * 128 + wv * 32;
    const int lrow  = lane & 15;
    const int klane = (lane >> 4) * 8;

    int  car[2]; bool val[2];
#pragma unroll
    for (int rf = 0; rf < 2; ++rf) {
        const int ar = r0 + rf * 16 + lrow;
        val[rf] = ar < M;
        car[rf] = val[rf] ? ar : (M - 1);
    }

    bf16x8 z8;
#pragma unroll
    for (int j = 0; j < 8; ++j) z8[j] = (__bf16)0.f;

    f32x4 acc[2][8];
#pragma unroll
    for (int rf = 0; rf < 2; ++rf)
#pragma unroll
        for (int cf = 0; cf < 8; ++cf) {
            f32x4 z; z[0] = 0.f; z[1] = 0.f; z[2] = 0.f; z[3] = 0.f;
            acc[rf][cf] = z;
        }

    const __bf16* xb = (const __bf16*)xdst;
    const float*  xf = (const float*)xdst;

#pragma unroll
    for (int ks = 0; ks < 8; ++ks) {
        const int koff = (ks & 3) * 32 + klane;
        bf16x8 a[2];
#pragma unroll
        for (int rf = 0; rf < 2; ++rf) {
            if (ks < 4) {
                const bf16x8 av = *reinterpret_cast<const bf16x8*>(
                    agg + (size_t)car[rf] * 128 + koff);
                a[rf] = val[rf] ? av : z8;
            } else if (XBF16) {
                const bf16x8 av = *reinterpret_cast<const bf16x8*>(
                    xb + (size_t)car[rf] * 128 + koff);
                a[rf] = val[rf] ? av : z8;
            } else {
                const float* ap = xf + (size_t)car[rf] * 128 + koff;
                const float4 f0 = *reinterpret_cast<const float4*>(ap);
                const float4 f1 = *reinterpret_cast<const float4*>(ap + 4);
                bf16x8 av;
                av[0] = (__bf16)f0.x; av[1] = (__bf16)f0.y; av[2] = (__bf16)f0.z; av[3] = (__bf16)f0.w;
                av[4] = (__bf16)f1.x; av[5] = (__bf16)f1.y; av[6] = (__bf16)f1.z; av[7] = (__bf16)f1.w;
                a[rf] = val[rf] ? av : z8;
            }
        }
        const bf16x8* wp8 = reinterpret_cast<const bf16x8*>(Wp) + (size_t)ks * 8 * 64 + lane;
        bf16x8 b[8];
#pragma unroll
        for (int cf = 0; cf < 8; ++cf) b[cf] = wp8[(size_t)cf * 64];
#pragma unroll
        for (int rf = 0; rf < 2; ++rf)
#pragma unroll
            for (int cf = 0; cf < 8; ++cf)
                acc[rf][cf] = __builtin_amdgcn_mfma_f32_16x16x32_bf16(a[rf], b[cf], acc[rf][cf], 0, 0, 0);
    }

    float bc[8];
#pragma unroll
    for (int cf = 0; cf < 8; ++cf) bc[cf] = bias[cf * 16 + lrow];

    const int rb = (lane >> 4) * 4;
#pragma unroll
    for (int cf = 0; cf < 8; ++cf) {
        float s = 0.f, q = 0.f;
#pragma unroll
        for (int rf = 0; rf < 2; ++rf) {
#pragma unroll
            for (int rr = 0; rr < 4; ++rr) {
                const int grow = r0 + rf * 16 + rb + rr;
                if (grow < M) {
                    const float hv = acc[rf][cf][rr] + bc[cf];
                    hout[(size_t)grow * 128 + cf * 16 + lrow] = (__bf16)hv;
                    s += hv; q += hv * hv;
                }
            }
        }
        s += __shfl_xor(s, 16); s += __shfl_xor(s, 32);
        q += __shfl_xor(q, 16); q += __shfl_xor(q, 32);
        if (lane < 16) {
            atomicAdd(&lsum[cf * 16 + lane], s);
            atomicAdd(&lsq [cf * 16 + lane], q);
        }
    }
    __syncthreads();
    if (tid < 128) {
        atomicAdd(&stats[tid],       lsum[tid]);
        atomicAdd(&stats[128 + tid], lsq[tid]);
    }
}

// ---------------------------------------------------------------- BN prep
__global__ void prep_kernel(const float* __restrict__ stats,
                            const float* __restrict__ gamma,
                            const float* __restrict__ beta,
                            float* __restrict__ ss, float invM)
{
    const int c = threadIdx.x;
    const float mu   = stats[c] * invM;
    const float var  = stats[128 + c] * invM - mu * mu;
    const float scal = gamma[c] * rsqrtf(var + 1e-5f);
    ss[c]       = scal;
    ss[128 + c] = beta[c] - mu * scal;
}

// ---------------------------------------------------------------- normalize + accumulate
// MODE 0: out(bf16) = v ; MODE 1: out(bf16) += v ; MODE 2: out(f32) += v ;
// MODE 3: out(f32) = resid(f32) + v
template<int MODE>
__global__ void __launch_bounds__(256) norm_kernel(const __bf16* __restrict__ h,
                                                   const float* __restrict__ ss,
                                                   const float* __restrict__ resid,
                                                   void* __restrict__ out, int M)
{
    const int t0   = blockIdx.x * 256 + threadIdx.x;
    const int nthr = gridDim.x * 256;
    const int c0   = (t0 & 15) * 8;
    float sc[8], sh[8];
#pragma unroll
    for (int j = 0; j < 8; ++j) { sc[j] = ss[c0 + j]; sh[j] = ss[128 + c0 + j]; }
    const int nch = M * 16;
    for (int ch = t0; ch < nch; ch += nthr) {
        const bf16x8 hv = *reinterpret_cast<const bf16x8*>(h + (size_t)ch * 8);
        float f[8];
#pragma unroll
        for (int j = 0; j < 8; ++j) f[j] = (float)hv[j] * sc[j] + sh[j];
        if constexpr (MODE == 0) {
            bf16x8 ov;
#pragma unroll
            for (int j = 0; j < 8; ++j) ov[j] = (__bf16)f[j];
            *reinterpret_cast<bf16x8*>((__bf16*)out + (size_t)ch * 8) = ov;
        } else if constexpr (MODE == 1) {
            __bf16* op = (__bf16*)out + (size_t)ch * 8;
            bf16x8 ov = *reinterpret_cast<const bf16x8*>(op);
#pragma unroll
            for (int j = 0; j < 8; ++j) ov[j] = (__bf16)((float)ov[j] + f[j]);
            *reinterpret_cast<bf16x8*>(op) = ov;
        } else if constexpr (MODE == 2) {
            float* op = (float*)out + (size_t)ch * 8;
            float4 o0 = *reinterpret_cast<float4*>(op);
            float4 o1 = *reinterpret_cast<float4*>(op + 4);
            o0.x += f[0]; o0.y += f[1]; o0.z += f[2]; o0.w += f[3];
            o1.x += f[4]; o1.y += f[5]; o1.z += f[6]; o1.w += f[7];
            *reinterpret_cast<float4*>(op)     = o0;
            *reinterpret_cast<float4*>(op + 4) = o1;
        } else {
            const float* rp = resid + (size_t)ch * 8;
            const float4 r0 = *reinterpret_cast<const float4*>(rp);
            const float4 r1 = *reinterpret_cast<const float4*>(rp + 4);
            float* op = (float*)out + (size_t)ch * 8;
            float4 o0, o1;
            o0.x = r0.x + f[0]; o0.y = r0.y + f[1]; o0.z = r0.z + f[2]; o0.w = r0.w + f[3];
            o1.x = r1.x + f[4]; o1.y = r1.y + f[5]; o1.z = r1.z + f[6]; o1.w = r1.w + f[7];
            *reinterpret_cast<float4*>(op)     = o0;
            *reinterpret_cast<float4*>(op + 4) = o1;
        }
    }
}

// ---------------------------------------------------------------- launch
extern "C" void kernel_launch(void* const* d_in, const int* in_sizes, int n_in,
                              void* d_out, int out_size, void* d_ws, size_t ws_size,
                              hipStream_t stream)
{
    const float* xin[3] = {(const float*)d_in[0], (const float*)d_in[1], (const float*)d_in[2]};
    const int N[3] = {in_sizes[0] / 128, in_sizes[1] / 128, in_sizes[2] / 128};
    const float* Wrel  = (const float*)d_in[12];
    const float* brel  = (const float*)d_in[13];
    const float* Wroot = (const float*)d_in[14];
    const float* gamma = (const float*)d_in[15];
    const float* beta  = (const float*)d_in[16];

    // ETS order: a2b b2a a2g g2a b2g g2b a2a b2b g2g  (atom=0,bond=1,global=2)
    const int cs[9] = {0, 1, 0, 2, 1, 2, 0, 1, 2};
    const int cd[9] = {1, 0, 2, 0, 2, 1, 0, 1, 2};

    const size_t nA = (size_t)N[0] * 128, nB = (size_t)N[1] * 128, nG = (size_t)N[2] * 128;
    const size_t off[3] = {0, nA, nA + nB};
    const size_t xtot = nA + nB + nG;
    size_t maxN = (size_t)N[0];
    if ((size_t)N[1] > maxN) maxN = N[1];
    if ((size_t)N[2] > maxN) maxN = N[2];

    // ws layout (~207 MB): x1(bf16) | agg(bf16,maxN) | h(bf16,maxN) | stats(18 slots) | ss(18) | Wp
    char* w = (char*)d_ws;
    __bf16* x1    = (__bf16*)w;  w += xtot * 2;
    __bf16* agg   = (__bf16*)w;  w += maxN * 128 * 2;
    __bf16* hbuf  = (__bf16*)w;  w += maxN * 128 * 2;
    float*  stats = (float*)w;   w += 18 * 256 * 4;
    float*  ss    = (float*)w;   w += 18 * 256 * 4;
    __bf16* Wp    = (__bf16*)w;
    (void)ws_size; (void)n_in; (void)out_size;

    pack_w<<<288, 256, 0, stream>>>(Wrel, Wroot, Wp);
    hipMemsetAsync(stats, 0, 18 * 256 * 4, stream);

    float* dout = (float*)d_out;

    for (int L = 0; L < 2; ++L) {
        for (int i = 0; i < 9; ++i) {
            const int s = cs[i], d = cd[i];
            const int E = in_sizes[3 + i] / 2;
            const int* ei = (const int*)d_in[3 + i];
            const int li = L * 9 + i;
            float* st = stats + li * 256;
            float* sl = ss + li * 256;

            hipMemsetAsync(agg, 0, (size_t)N[d] * 128 * 2, stream);
            int sb = (E + 3) / 4; if (sb > 2048) sb = 2048; if (sb < 1) sb = 1;
            if (L == 0) scatter_f32 <<<sb, 256, 0, stream>>>(xin[s], ei, E, agg);
            else        scatter_bf16<<<sb, 256, 0, stream>>>(x1 + off[s], ei, E, agg);

            const int gb = (N[d] + 127) / 128;
            if (L == 0)
                gemm_kernel<false><<<gb, 256, 0, stream>>>(agg, (const void*)xin[d],
                    Wp + (size_t)li * 32768, brel + li * 128, hbuf, st, N[d]);
            else
                gemm_kernel<true ><<<gb, 256, 0, stream>>>(agg, (const void*)(x1 + off[d]),
                    Wp + (size_t)li * 32768, brel + li * 128, hbuf, st, N[d]);

            prep_kernel<<<1, 128, 0, stream>>>(st, gamma + li * 128, beta + li * 128,
                                               sl, 1.0f / (float)N[d]);

            const long long nch = (long long)N[d] * 16;
            int nb = (int)((nch + 255) / 256); if (nb > 2048) nb = 2048;
            if (L == 0) {
                if (i < 3) norm_kernel<0><<<nb, 256, 0, stream>>>(hbuf, sl, nullptr, (void*)(x1 + off[d]), N[d]);
                else       norm_kernel<1><<<nb, 256, 0, stream>>>(hbuf, sl, nullptr, (void*)(x1 + off[d]), N[d]);
            } else {
                if (i < 3) norm_kernel<3><<<nb, 256, 0, stream>>>(hbuf, sl, xin[d], (void*)(dout + off[d]), N[d]);
                else       norm_kernel<2><<<nb, 256, 0, stream>>>(hbuf, sl, nullptr, (void*)(dout + off[d]), N[d]);
            }
        }
    }
}

// Round 3
// 2731.598 us; speedup vs baseline: 2.1616x; 1.0026x over previous
//
#include <hip/hip_runtime.h>
#include <hip/hip_bf16.h>

typedef __bf16 bf16x8 __attribute__((ext_vector_type(8)));
typedef float  f32x4  __attribute__((ext_vector_type(4)));

// ---------------------------------------------------------------- pack W
// Layout: [li=L*9+i][ks(8)][cf(8)][lane(64)][j(8)]  (bf16)
// k = ks*32 + (lane>>4)*8 + j ; col = cf*16 + (lane&15)
// k < 128 -> W_rel[li][k][col], else W_root[li][k-128][col]
__global__ void __launch_bounds__(256) pack_w(const float* __restrict__ Wrel,
                                              const float* __restrict__ Wroot,
                                              __bf16* __restrict__ Wp)
{
    const int idx = blockIdx.x * 256 + threadIdx.x;
    if (idx >= 2 * 9 * 8 * 8 * 64) return;
    const int lane = idx & 63;
    int t = idx >> 6;
    const int cf = t & 7; t >>= 3;
    const int ks = t & 7; t >>= 3;
    const int li = t;  // 0..17
    const int col = cf * 16 + (lane & 15);
    const int kb  = ks * 32 + (lane >> 4) * 8;
    bf16x8 o;
#pragma unroll
    for (int j = 0; j < 8; ++j) {
        const int k = kb + j;
        const float v = (k < 128)
            ? Wrel [((size_t)li * 128 + k)        * 128 + col]
            : Wroot[((size_t)li * 128 + (k - 128)) * 128 + col];
        o[j] = (__bf16)v;
    }
    *reinterpret_cast<bf16x8*>(Wp + (size_t)idx * 8) = o;
}

// ---------------------------------------------------------------- scatter
// agg(bf16)[dst] += x_src[src]; one wave per edge, one packed-bf16x2 atomic per lane.
__device__ __forceinline__ void pk_atomic(__bf16* p, uint32_t pk)
{
    const uint64_t addr = (uint64_t)p;
    asm volatile("global_atomic_pk_add_bf16 %0, %1, off" :: "v"(addr), "v"(pk) : "memory");
}

__global__ void __launch_bounds__(256) scatter_f32(const float* __restrict__ xsrc,
                                                   const int* __restrict__ ei, int E,
                                                   __bf16* __restrict__ agg)
{
    const int lane = threadIdx.x & 63;
    const int gw = (blockIdx.x * 256 + threadIdx.x) >> 6;
    const int nw = (gridDim.x * 256) >> 6;
    for (int e = gw; e < E; e += nw) {
        const int s = ei[e];
        const int d = ei[E + e];
        const float2 v = *reinterpret_cast<const float2*>(xsrc + (size_t)s * 128 + lane * 2);
        union { __bf16 b[2]; uint32_t u; } cv;
        cv.b[0] = (__bf16)v.x; cv.b[1] = (__bf16)v.y;
        pk_atomic(agg + (size_t)d * 128 + lane * 2, cv.u);
    }
}

__global__ void __launch_bounds__(256) scatter_bf16(const __bf16* __restrict__ xsrc,
                                                    const int* __restrict__ ei, int E,
                                                    __bf16* __restrict__ agg)
{
    const int lane = threadIdx.x & 63;
    const int gw = (blockIdx.x * 256 + threadIdx.x) >> 6;
    const int nw = (gridDim.x * 256) >> 6;
    for (int e = gw; e < E; e += nw) {
        const int s = ei[e];
        const int d = ei[E + e];
        const uint32_t pk = *reinterpret_cast<const uint32_t*>(xsrc + (size_t)s * 128 + lane * 2);
        pk_atomic(agg + (size_t)d * 128 + lane * 2, pk);
    }
}

// ---------------------------------------------------------------- GEMM + BN stats
// h[M,128] = [agg | x_dst](M,256) @ Wp(256,128) + bias ; stats[0:128]=colsum(h), [128:256]=colsum(h^2)
// block = 256 thr (4 waves), tile = 128 rows; wave w owns rows w*32..w*32+31 (2 row-frags),
// all 8 col-frags. 16x16x32 bf16 MFMA. A direct from global, B from packed global (L2).
template<bool XBF16>
__global__ void __launch_bounds__(256) gemm_kernel(const __bf16* __restrict__ agg,
                                                   const void* __restrict__ xdst,
                                                   const __bf16* __restrict__ Wp,
                                                   const float* __restrict__ bias,
                                                   __bf16* __restrict__ hout,
                                                   float* __restrict__ stats, int M)
{
    __shared__ float lsum[128];
    __shared__ float lsq[128];
    const int tid  = threadIdx.x;
    const int lane = tid & 63;
    const int wv   = tid >> 6;
    if (tid < 128) { lsum[tid] = 0.f; lsq[tid] = 0.f; }
    __syncthreads();

    const int r0    = blockIdx.x * 128 + wv * 32;
    const int lrow  = lane & 15;
    const int klane = (lane >> 4) * 8;

    int  car[2]; bool val[2];
#pragma unroll
    for (int rf = 0; rf < 2; ++rf) {
        const int ar = r0 + rf * 16 + lrow;
        val[rf] = ar < M;
        car[rf] = val[rf] ? ar : (M - 1);
    }

    bf16x8 z8;
#pragma unroll
    for (int j = 0; j < 8; ++j) z8[j] = (__bf16)0.f;

    f32x4 acc[2][8];
#pragma unroll
    for (int rf = 0; rf < 2; ++rf)
#pragma unroll
        for (int cf = 0; cf < 8; ++cf) {
            f32x4 z; z[0] = 0.f; z[1] = 0.f; z[2] = 0.f; z[3] = 0.f;
            acc[rf][cf] = z;
        }

    const __bf16* xb = (const __bf16*)xdst;
    const float*  xf = (const float*)xdst;

#pragma unroll
    for (int ks = 0; ks < 8; ++ks) {
        const int koff = (ks & 3) * 32 + klane;
        bf16x8 a[2];
#pragma unroll
        for (int rf = 0; rf < 2; ++rf) {
            if (ks < 4) {
                const bf16x8 av = *reinterpret_cast<const bf16x8*>(
                    agg + (size_t)car[rf] * 128 + koff);
                a[rf] = val[rf] ? av : z8;
            } else if (XBF16) {
                const bf16x8 av = *reinterpret_cast<const bf16x8*>(
                    xb + (size_t)car[rf] * 128 + koff);
                a[rf] = val[rf] ? av : z8;
            } else {
                const float* ap = xf + (size_t)car[rf] * 128 + koff;
                const float4 f0 = *reinterpret_cast<const float4*>(ap);
                const float4 f1 = *reinterpret_cast<const float4*>(ap + 4);
                bf16x8 av;
                av[0] = (__bf16)f0.x; av[1] = (__bf16)f0.y; av[2] = (__bf16)f0.z; av[3] = (__bf16)f0.w;
                av[4] = (__bf16)f1.x; av[5] = (__bf16)f1.y; av[6] = (__bf16)f1.z; av[7] = (__bf16)f1.w;
                a[rf] = val[rf] ? av : z8;
            }
        }
        const bf16x8* wp8 = reinterpret_cast<const bf16x8*>(Wp) + (size_t)ks * 8 * 64 + lane;
        bf16x8 b[8];
#pragma unroll
        for (int cf = 0; cf < 8; ++cf) b[cf] = wp8[(size_t)cf * 64];
#pragma unroll
        for (int rf = 0; rf < 2; ++rf)
#pragma unroll
            for (int cf = 0; cf < 8; ++cf)
                acc[rf][cf] = __builtin_amdgcn_mfma_f32_16x16x32_bf16(a[rf], b[cf], acc[rf][cf], 0, 0, 0);
    }

    float bc[8];
#pragma unroll
    for (int cf = 0; cf < 8; ++cf) bc[cf] = bias[cf * 16 + lrow];

    const int rb = (lane >> 4) * 4;
#pragma unroll
    for (int cf = 0; cf < 8; ++cf) {
        float s = 0.f, q = 0.f;
#pragma unroll
        for (int rf = 0; rf < 2; ++rf) {
#pragma unroll
            for (int rr = 0; rr < 4; ++rr) {
                const int grow = r0 + rf * 16 + rb + rr;
                if (grow < M) {
                    const float hv = acc[rf][cf][rr] + bc[cf];
                    hout[(size_t)grow * 128 + cf * 16 + lrow] = (__bf16)hv;
                    s += hv; q += hv * hv;
                }
            }
        }
        s += __shfl_xor(s, 16); s += __shfl_xor(s, 32);
        q += __shfl_xor(q, 16); q += __shfl_xor(q, 32);
        if (lane < 16) {
            atomicAdd(&lsum[cf * 16 + lane], s);
            atomicAdd(&lsq [cf * 16 + lane], q);
        }
    }
    __syncthreads();
    if (tid < 128) {
        atomicAdd(&stats[tid],       lsum[tid]);
        atomicAdd(&stats[128 + tid], lsq[tid]);
    }
}

// ---------------------------------------------------------------- BN prep
__global__ void prep_kernel(const float* __restrict__ stats,
                            const float* __restrict__ gamma,
                            const float* __restrict__ beta,
                            float* __restrict__ ss, float invM)
{
    const int c = threadIdx.x;
    const float mu   = stats[c] * invM;
    const float var  = stats[128 + c] * invM - mu * mu;
    const float scal = gamma[c] * rsqrtf(var + 1e-5f);
    ss[c]       = scal;
    ss[128 + c] = beta[c] - mu * scal;
}

// ---------------------------------------------------------------- normalize + accumulate
// MODE 0: out(bf16) = v ; MODE 1: out(bf16) += v ; MODE 2: out(f32) += v ;
// MODE 3: out(f32) = resid(f32) + v
template<int MODE>
__global__ void __launch_bounds__(256) norm_kernel(const __bf16* __restrict__ h,
                                                   const float* __restrict__ ss,
                                                   const float* __restrict__ resid,
                                                   void* __restrict__ out, int M)
{
    const int t0   = blockIdx.x * 256 + threadIdx.x;
    const int nthr = gridDim.x * 256;
    const int c0   = (t0 & 15) * 8;
    float sc[8], sh[8];
#pragma unroll
    for (int j = 0; j < 8; ++j) { sc[j] = ss[c0 + j]; sh[j] = ss[128 + c0 + j]; }
    const int nch = M * 16;
    for (int ch = t0; ch < nch; ch += nthr) {
        const bf16x8 hv = *reinterpret_cast<const bf16x8*>(h + (size_t)ch * 8);
        float f[8];
#pragma unroll
        for (int j = 0; j < 8; ++j) f[j] = (float)hv[j] * sc[j] + sh[j];
        if constexpr (MODE == 0) {
            bf16x8 ov;
#pragma unroll
            for (int j = 0; j < 8; ++j) ov[j] = (__bf16)f[j];
            *reinterpret_cast<bf16x8*>((__bf16*)out + (size_t)ch * 8) = ov;
        } else if constexpr (MODE == 1) {
            __bf16* op = (__bf16*)out + (size_t)ch * 8;
            bf16x8 ov = *reinterpret_cast<const bf16x8*>(op);
#pragma unroll
            for (int j = 0; j < 8; ++j) ov[j] = (__bf16)((float)ov[j] + f[j]);
            *reinterpret_cast<bf16x8*>(op) = ov;
        } else if constexpr (MODE == 2) {
            float* op = (float*)out + (size_t)ch * 8;
            float4 o0 = *reinterpret_cast<float4*>(op);
            float4 o1 = *reinterpret_cast<float4*>(op + 4);
            o0.x += f[0]; o0.y += f[1]; o0.z += f[2]; o0.w += f[3];
            o1.x += f[4]; o1.y += f[5]; o1.z += f[6]; o1.w += f[7];
            *reinterpret_cast<float4*>(op)     = o0;
            *reinterpret_cast<float4*>(op + 4) = o1;
        } else {
            const float* rp = resid + (size_t)ch * 8;
            const float4 r0 = *reinterpret_cast<const float4*>(rp);
            const float4 r1 = *reinterpret_cast<const float4*>(rp + 4);
            float* op = (float*)out + (size_t)ch * 8;
            float4 o0, o1;
            o0.x = r0.x + f[0]; o0.y = r0.y + f[1]; o0.z = r0.z + f[2]; o0.w = r0.w + f[3];
            o1.x = r1.x + f[4]; o1.y = r1.y + f[5]; o1.z = r1.z + f[6]; o1.w = r1.w + f[7];
            *reinterpret_cast<float4*>(op)     = o0;
            *reinterpret_cast<float4*>(op + 4) = o1;
        }
    }
}

// ---------------------------------------------------------------- launch
extern "C" void kernel_launch(void* const* d_in, const int* in_sizes, int n_in,
                              void* d_out, int out_size, void* d_ws, size_t ws_size,
                              hipStream_t stream)
{
    const float* xin[3] = {(const float*)d_in[0], (const float*)d_in[1], (const float*)d_in[2]};
    const int N[3] = {in_sizes[0] / 128, in_sizes[1] / 128, in_sizes[2] / 128};
    const float* Wrel  = (const float*)d_in[12];
    const float* brel  = (const float*)d_in[13];
    const float* Wroot = (const float*)d_in[14];
    const float* gamma = (const float*)d_in[15];
    const float* beta  = (const float*)d_in[16];

    // ETS order: a2b b2a a2g g2a b2g g2b a2a b2b g2g  (atom=0,bond=1,global=2)
    const int cs[9] = {0, 1, 0, 2, 1, 2, 0, 1, 2};
    const int cd[9] = {1, 0, 2, 0, 2, 1, 0, 1, 2};

    const size_t nA = (size_t)N[0] * 128, nB = (size_t)N[1] * 128, nG = (size_t)N[2] * 128;
    const size_t off[3] = {0, nA, nA + nB};
    const size_t xtot = nA + nB + nG;
    size_t maxN = (size_t)N[0];
    if ((size_t)N[1] > maxN) maxN = N[1];
    if ((size_t)N[2] > maxN) maxN = N[2];

    // ws layout (~207 MB): x1(bf16) | agg(bf16,maxN) | h(bf16,maxN) | stats(18 slots) | ss(18) | Wp
    char* w = (char*)d_ws;
    __bf16* x1    = (__bf16*)w;  w += xtot * 2;
    __bf16* agg   = (__bf16*)w;  w += maxN * 128 * 2;
    __bf16* hbuf  = (__bf16*)w;  w += maxN * 128 * 2;
    float*  stats = (float*)w;   w += 18 * 256 * 4;
    float*  ss    = (float*)w;   w += 18 * 256 * 4;
    __bf16* Wp    = (__bf16*)w;
    (void)ws_size; (void)n_in; (void)out_size;

    pack_w<<<288, 256, 0, stream>>>(Wrel, Wroot, Wp);
    hipMemsetAsync(stats, 0, 18 * 256 * 4, stream);

    float* dout = (float*)d_out;

    for (int L = 0; L < 2; ++L) {
        for (int i = 0; i < 9; ++i) {
            const int s = cs[i], d = cd[i];
            const int E = in_sizes[3 + i] / 2;
            const int* ei = (const int*)d_in[3 + i];
            const int li = L * 9 + i;
            float* st = stats + li * 256;
            float* sl = ss + li * 256;

            hipMemsetAsync(agg, 0, (size_t)N[d] * 128 * 2, stream);
            int sb = (E + 3) / 4; if (sb > 2048) sb = 2048; if (sb < 1) sb = 1;
            if (L == 0) scatter_f32 <<<sb, 256, 0, stream>>>(xin[s], ei, E, agg);
            else        scatter_bf16<<<sb, 256, 0, stream>>>(x1 + off[s], ei, E, agg);

            const int gb = (N[d] + 127) / 128;
            if (L == 0)
                gemm_kernel<false><<<gb, 256, 0, stream>>>(agg, (const void*)xin[d],
                    Wp + (size_t)li * 32768, brel + li * 128, hbuf, st, N[d]);
            else
                gemm_kernel<true ><<<gb, 256, 0, stream>>>(agg, (const void*)(x1 + off[d]),
                    Wp + (size_t)li * 32768, brel + li * 128, hbuf, st, N[d]);

            prep_kernel<<<1, 128, 0, stream>>>(st, gamma + li * 128, beta + li * 128,
                                               sl, 1.0f / (float)N[d]);

            const long long nch = (long long)N[d] * 16;
            int nb = (int)((nch + 255) / 256); if (nb > 2048) nb = 2048;
            if (L == 0) {
                if (i < 3) norm_kernel<0><<<nb, 256, 0, stream>>>(hbuf, sl, nullptr, (void*)(x1 + off[d]), N[d]);
                else       norm_kernel<1><<<nb, 256, 0, stream>>>(hbuf, sl, nullptr, (void*)(x1 + off[d]), N[d]);
            } else {
                if (i < 3) norm_kernel<3><<<nb, 256, 0, stream>>>(hbuf, sl, xin[d], (void*)(dout + off[d]), N[d]);
                else       norm_kernel<2><<<nb, 256, 0, stream>>>(hbuf, sl, nullptr, (void*)(dout + off[d]), N[d]);
            }
        }
    }
}